// Round 1
// baseline (24.821 us; speedup 1.0000x reference)
//
#include <hip/hip_runtime.h>

#define NB   64
#define NPT  8192
#define SSZ  384
#define GSZ  128

// Per-point permutohedral computation. Must be bitwise-deterministic and
// replicate XLA-CPU f32 semantics:
//  - pc = x*190.0f           (single IEEE mul)
//  - elevated = E @ pc       (Eigen gemm: FMA chain, k ascending)
//  - greedy = rint(ev/3)*3   (IEEE div, round-half-even)
// Downstream (rank, remainder fixup, offsets) is exact integer math.
__device__ __forceinline__ void compute_point(const float* __restrict__ x, int b, int n,
                                              int& g0o, int& g1o, int& r0o, int& r1o) {
    // (float)np.sqrt(6.0)
    const float s6 = (float)2.449489742783178098197284074705891391989;
    const float ca = 2.0f / s6;   // compile-time IEEE fold, same bits as numpy
    const float cb = -1.0f / s6;
    const float* xb = x + (size_t)b * 6 * NPT + n;
    float p0 = xb[0 * NPT] * 190.0f;
    float p1 = xb[1 * NPT] * 190.0f;
    float p2 = xb[2 * NPT] * 190.0f;
    // E rows: [ca cb cb; cb ca cb; cb cb ca], FMA-chain j=0,1,2 (Eigen gebp order)
    float ev0 = __builtin_fmaf(cb, p2, __builtin_fmaf(cb, p1, ca * p0));
    float ev1 = __builtin_fmaf(cb, p2, __builtin_fmaf(ca, p1, cb * p0));
    float ev2 = __builtin_fmaf(ca, p2, __builtin_fmaf(cb, p1, cb * p0));
    float q0 = ev0 / 3.0f, q1 = ev1 / 3.0f, q2 = ev2 / 3.0f;
    float rg0 = rintf(q0), rg1 = rintf(q1), rg2 = rintf(q2);  // round-half-even
    int gi0 = (int)rg0 * 3, gi1 = (int)rg1 * 3, gi2 = (int)rg2 * 3;
    // el_minus_gr (pre-fixup), used only for ordering -> rank
    float e0 = ev0 - rg0 * 3.0f;
    float e1 = ev1 - rg1 * 3.0f;
    float e2 = ev2 - rg2 * 3.0f;
    // rank[i] = #{j: e[j]>e[i]} + #{j: e[j]==e[i], j<i}  (stable descending argsort)
    int rk0 = (int)(e1 > e0) + (int)(e2 > e0);
    int rk1 = (int)(e0 > e1) + (int)(e0 == e1) + (int)(e2 > e1);
    int rk2 = (int)(e0 > e2) + (int)(e0 == e2) + (int)(e1 > e2) + (int)(e1 == e2);
    int rs = (gi0 + gi1 + gi2) / 3;  // exact: sum is a multiple of 3, in {-3,0,3}
    if (rs > 0) {
        if (rk0 >= 3 - rs) { gi0 -= 3; rk0 -= 3; }
        if (rk1 >= 3 - rs) { gi1 -= 3; rk1 -= 3; }
        if (rk2 >= 3 - rs) { gi2 -= 3; rk2 -= 3; }
    } else if (rs < 0) {
        if (rk0 < -rs) { gi0 += 3; rk0 += 3; }
        if (rk1 < -rs) { gi1 += 3; rk1 += 3; }
        if (rk2 < -rs) { gi2 += 3; rk2 += 3; }
    }
    rk0 += rs; rk1 += rs;
    g0o = gi0; g1o = gi1; r0o = rk0; r1o = rk1;
}

// offset[b,d] = min_n (greedy_d - rank_d). One block per batch.
__global__ void kmin(const float* __restrict__ x, int* __restrict__ offs) {
    int b = blockIdx.x;
    int t = threadIdx.x;
    int m0 = 0x7fffffff, m1 = 0x7fffffff;
    for (int n = t; n < NPT; n += 256) {
        int g0, g1, r0, r1;
        compute_point(x, b, n, g0, g1, r0, r1);
        m0 = min(m0, g0 - r0);
        m1 = min(m1, g1 - r1);
    }
    __shared__ int s0[256], s1[256];
    s0[t] = m0; s1[t] = m1;
    __syncthreads();
    for (int w = 128; w > 0; w >>= 1) {
        if (t < w) { s0[t] = min(s0[t], s0[t + w]); s1[t] = min(s1[t], s1[t + w]); }
        __syncthreads();
    }
    if (t == 0) { offs[b * 2 + 0] = s0[0]; offs[b * 2 + 1] = s1[0]; }
}

__global__ void kzero(float4* __restrict__ out, int n4) {
    int i = blockIdx.x * blockDim.x + threadIdx.x;
    if (i < n4) out[i] = make_float4(0.f, 0.f, 0.f, 0.f);
}

__global__ void kscatter(const float* __restrict__ x, const int* __restrict__ offs,
                         float* __restrict__ out) {
    int idx = blockIdx.x * blockDim.x + threadIdx.x;
    if (idx >= NB * NPT) return;
    int b = idx / NPT, n = idx % NPT;
    int g0, g1, r0, r1;
    compute_point(x, b, n, g0, g1, r0, r1);
    int c0 = g0 - offs[b * 2 + 0];
    int c1 = g1 - offs[b * 2 + 1];
    if (c0 < SSZ && c1 < SSZ) {
        // c_d >= 0 always (offset <= g - r <= g); c_d mod 3 == pts_pick_d,
        // so the sampled-grid index is simply c_d / 3.
        int i = c0 / 3, j = c1 / 3;
        const float* xb = x + (size_t)b * 6 * NPT + n;
        float* ob = out + (size_t)b * 3 * GSZ * GSZ + (size_t)i * GSZ + j;
        atomicAdd(ob + 0 * GSZ * GSZ, xb[3 * NPT]);
        atomicAdd(ob + 1 * GSZ * GSZ, xb[4 * NPT]);
        atomicAdd(ob + 2 * GSZ * GSZ, xb[5 * NPT]);
    }
}

extern "C" void kernel_launch(void* const* d_in, const int* in_sizes, int n_in,
                              void* d_out, int out_size, void* d_ws, size_t ws_size,
                              hipStream_t stream) {
    const float* x = (const float*)d_in[0];
    float* out = (float*)d_out;
    int* offs = (int*)d_ws;  // 128 ints

    int n4 = out_size / 4;  // 3145728/4 = 786432
    kzero<<<(n4 + 255) / 256, 256, 0, stream>>>((float4*)out, n4);
    kmin<<<NB, 256, 0, stream>>>(x, offs);
    kscatter<<<(NB * NPT) / 256, 256, 0, stream>>>(x, offs, out);
}

// Round 2
// 17.552 us; speedup vs baseline: 1.4142x; 1.4142x over previous
//
#include <hip/hip_runtime.h>

#define NB   64
#define NPT  8192
#define SSZ  384
#define GSZ  128
#define TPB  1024
#define PPT  (NPT / TPB)   // 8 points per thread
#define ZPT  (3 * GSZ * GSZ / 4 / TPB)  // 12 float4 zero-stores per thread

// Per-point permutohedral computation. Bitwise-replicates XLA-CPU f32:
//  - pc = x*190.0f           (single IEEE mul)
//  - elevated = E @ pc       (Eigen gemm: FMA chain, k ascending)
//  - greedy = rint(ev/3)*3   (IEEE div, round-half-even)
// Downstream (rank, remainder fixup, offsets) is exact integer math.
// Verified absmax == 0.0 in round 1.
__device__ __forceinline__ void compute_point(const float* __restrict__ x, int b, int n,
                                              int& g0o, int& g1o, int& r0o, int& r1o) {
    const float s6 = (float)2.449489742783178098197284074705891391989;
    const float ca = 2.0f / s6;
    const float cb = -1.0f / s6;
    const float* xb = x + (size_t)b * 6 * NPT + n;
    float p0 = xb[0 * NPT] * 190.0f;
    float p1 = xb[1 * NPT] * 190.0f;
    float p2 = xb[2 * NPT] * 190.0f;
    float ev0 = __builtin_fmaf(cb, p2, __builtin_fmaf(cb, p1, ca * p0));
    float ev1 = __builtin_fmaf(cb, p2, __builtin_fmaf(ca, p1, cb * p0));
    float ev2 = __builtin_fmaf(ca, p2, __builtin_fmaf(cb, p1, cb * p0));
    float q0 = ev0 / 3.0f, q1 = ev1 / 3.0f, q2 = ev2 / 3.0f;
    float rg0 = rintf(q0), rg1 = rintf(q1), rg2 = rintf(q2);  // round-half-even
    int gi0 = (int)rg0 * 3, gi1 = (int)rg1 * 3, gi2 = (int)rg2 * 3;
    float e0 = ev0 - rg0 * 3.0f;
    float e1 = ev1 - rg1 * 3.0f;
    float e2 = ev2 - rg2 * 3.0f;
    // stable descending argsort -> rank
    int rk0 = (int)(e1 > e0) + (int)(e2 > e0);
    int rk1 = (int)(e0 > e1) + (int)(e0 == e1) + (int)(e2 > e1);
    int rk2 = (int)(e0 > e2) + (int)(e0 == e2) + (int)(e1 > e2) + (int)(e1 == e2);
    int rs = (gi0 + gi1 + gi2) / 3;
    if (rs > 0) {
        if (rk0 >= 3 - rs) { gi0 -= 3; rk0 -= 3; }
        if (rk1 >= 3 - rs) { gi1 -= 3; rk1 -= 3; }
        if (rk2 >= 3 - rs) { gi2 -= 3; rk2 -= 3; }
    } else if (rs < 0) {
        if (rk0 < -rs) { gi0 += 3; rk0 += 3; }
        if (rk1 < -rs) { gi1 += 3; rk1 += 3; }
        if (rk2 < -rs) { gi2 += 3; rk2 += 3; }
    }
    rk0 += rs; rk1 += rs;
    g0o = gi0; g1o = gi1; r0o = rk0; r1o = rk1;
}

// One block per batch: zero own output slice, compute per-point keys once
// (packed in LDS), block-reduce the per-batch offset, scatter. No cross-block
// dependency -> single launch.
__global__ __launch_bounds__(TPB) void kfused(const float* __restrict__ x,
                                              float* __restrict__ out) {
    const int b = blockIdx.x;
    const int t = threadIdx.x;
    __shared__ int pk[NPT];        // packed (g0,g1) int16 pairs
    __shared__ int red0[16], red1[16], offsh[2];

    // zero this batch's output slice (only block b ever writes it)
    float4* ob4 = (float4*)(out + (size_t)b * 3 * GSZ * GSZ);
    const float4 z4 = make_float4(0.f, 0.f, 0.f, 0.f);
#pragma unroll
    for (int k = 0; k < ZPT; ++k) ob4[t + k * TPB] = z4;

    // per-point keys + per-thread min of (g - rank)
    int m0 = 0x7fffffff, m1 = 0x7fffffff;
#pragma unroll
    for (int k = 0; k < PPT; ++k) {
        int n = t + k * TPB;
        int g0, g1, r0, r1;
        compute_point(x, b, n, g0, g1, r0, r1);
        m0 = min(m0, g0 - r0);
        m1 = min(m1, g1 - r1);
        pk[n] = (g0 & 0xffff) | (g1 << 16);
    }

    // wave-level min, then cross-wave via LDS
    for (int o = 32; o; o >>= 1) {
        m0 = min(m0, __shfl_down(m0, o));
        m1 = min(m1, __shfl_down(m1, o));
    }
    const int w = t >> 6;
    if ((t & 63) == 0) { red0[w] = m0; red1[w] = m1; }
    __syncthreads();   // also orders the global zero-stores before the atomics
    if (t == 0) {
        int a0 = red0[0], a1 = red1[0];
        for (int i = 1; i < TPB / 64; ++i) { a0 = min(a0, red0[i]); a1 = min(a1, red1[i]); }
        offsh[0] = a0; offsh[1] = a1;
    }
    __syncthreads();
    const int off0 = offsh[0], off1 = offsh[1];

    // scatter surviving points (sparse: ~0.1%)
    const float* xb = x + (size_t)b * 6 * NPT;
    float* ob = out + (size_t)b * 3 * GSZ * GSZ;
#pragma unroll
    for (int k = 0; k < PPT; ++k) {
        int n = t + k * TPB;
        int p = pk[n];
        int g0 = (int)(short)(p & 0xffff);
        int g1 = p >> 16;                    // arithmetic shift sign-extends
        int c0 = g0 - off0, c1 = g1 - off1;  // c >= 0 always (off <= g - r <= g)
        if (c0 < SSZ && c1 < SSZ) {
            int i = c0 / 3, j = c1 / 3;      // c mod 3 == pts_pick -> exact sub-grid hit
            float* o = ob + (size_t)i * GSZ + j;
            atomicAdd(o + 0 * GSZ * GSZ, xb[3 * NPT + n]);
            atomicAdd(o + 1 * GSZ * GSZ, xb[4 * NPT + n]);
            atomicAdd(o + 2 * GSZ * GSZ, xb[5 * NPT + n]);
        }
    }
}

extern "C" void kernel_launch(void* const* d_in, const int* in_sizes, int n_in,
                              void* d_out, int out_size, void* d_ws, size_t ws_size,
                              hipStream_t stream) {
    const float* x = (const float*)d_in[0];
    float* out = (float*)d_out;
    kfused<<<NB, TPB, 0, stream>>>(x, out);
}

// Round 3
// 13.719 us; speedup vs baseline: 1.8092x; 1.2794x over previous
//
#include <hip/hip_runtime.h>

#define NB    64
#define NPT   8192
#define SSZ   384
#define GSZ   128
#define TPB   256
#define BPB   32                    // blocks per batch
#define NBLK  (NB * BPB)            // 2048
#define OUT4  (3 * GSZ * GSZ * NB / 4)   // 786432 float4s
#define NTHR  (NBLK * TPB)          // 524288

// Per-point permutohedral computation. Bitwise-replicates XLA-CPU f32:
//  - pc = x*190.0f           (single IEEE mul)
//  - elevated = E @ pc       (Eigen gemm: FMA chain, k ascending)
//  - greedy = rint(ev/3)*3   (IEEE div, round-half-even)
// Downstream is exact integer math. Verified absmax == 0.0 (rounds 1-2).
__device__ __forceinline__ void compute_point(const float* __restrict__ x, int b, int n,
                                              int& g0o, int& g1o, int& r0o, int& r1o) {
    const float s6 = (float)2.449489742783178098197284074705891391989;
    const float ca = 2.0f / s6;
    const float cb = -1.0f / s6;
    const float* xb = x + (size_t)b * 6 * NPT + n;
    float p0 = xb[0 * NPT] * 190.0f;
    float p1 = xb[1 * NPT] * 190.0f;
    float p2 = xb[2 * NPT] * 190.0f;
    float ev0 = __builtin_fmaf(cb, p2, __builtin_fmaf(cb, p1, ca * p0));
    float ev1 = __builtin_fmaf(cb, p2, __builtin_fmaf(ca, p1, cb * p0));
    float ev2 = __builtin_fmaf(ca, p2, __builtin_fmaf(cb, p1, cb * p0));
    float q0 = ev0 / 3.0f, q1 = ev1 / 3.0f, q2 = ev2 / 3.0f;
    float rg0 = rintf(q0), rg1 = rintf(q1), rg2 = rintf(q2);  // round-half-even
    int gi0 = (int)rg0 * 3, gi1 = (int)rg1 * 3, gi2 = (int)rg2 * 3;
    float e0 = ev0 - rg0 * 3.0f;
    float e1 = ev1 - rg1 * 3.0f;
    float e2 = ev2 - rg2 * 3.0f;
    int rk0 = (int)(e1 > e0) + (int)(e2 > e0);
    int rk1 = (int)(e0 > e1) + (int)(e0 == e1) + (int)(e2 > e1);
    int rk2 = (int)(e0 > e2) + (int)(e0 == e2) + (int)(e1 > e2) + (int)(e1 == e2);
    int rs = (gi0 + gi1 + gi2) / 3;
    if (rs > 0) {
        if (rk0 >= 3 - rs) { gi0 -= 3; rk0 -= 3; }
        if (rk1 >= 3 - rs) { gi1 -= 3; rk1 -= 3; }
        if (rk2 >= 3 - rs) { gi2 -= 3; rk2 -= 3; }
    } else if (rs < 0) {
        if (rk0 < -rs) { gi0 += 3; rk0 += 3; }
        if (rk1 < -rs) { gi1 += 3; rk1 += 3; }
        if (rk2 < -rs) { gi2 += 3; rk2 += 3; }
    }
    rk0 += rs; rk1 += rs;
    g0o = gi0; g1o = gi1; r0o = rk0; r1o = rk1;
}

// Kernel A (full chip): zero output + per-block min of (g - rank) -> bm[bid].
__global__ __launch_bounds__(TPB) void kA(const float* __restrict__ x,
                                          float* __restrict__ out,
                                          int* __restrict__ bm) {
    const int bid = blockIdx.x, t = threadIdx.x;
    const int gid = bid * TPB + t;

    // zero the output (grid-wide index, decoupled from batch mapping)
    float4* o4 = (float4*)out;
    const float4 z4 = make_float4(0.f, 0.f, 0.f, 0.f);
    o4[gid] = z4;
    int g2 = gid + NTHR;
    if (g2 < OUT4) o4[g2] = z4;

    const int b = bid >> 5;              // BPB = 32
    const int n = ((bid & 31) << 8) | t; // 256 points per block, coalesced
    int g0, g1, r0, r1;
    compute_point(x, b, n, g0, g1, r0, r1);
    int m0 = g0 - r0, m1 = g1 - r1;

    for (int o = 32; o; o >>= 1) {
        m0 = min(m0, __shfl_down(m0, o));
        m1 = min(m1, __shfl_down(m1, o));
    }
    __shared__ int red0[4], red1[4];
    if ((t & 63) == 0) { red0[t >> 6] = m0; red1[t >> 6] = m1; }
    __syncthreads();
    if (t == 0) {
        int a0 = min(min(red0[0], red0[1]), min(red0[2], red0[3]));
        int a1 = min(min(red1[0], red1[1]), min(red1[2], red1[3]));
        bm[bid * 2 + 0] = a0;
        bm[bid * 2 + 1] = a1;
    }
}

// Kernel B (full chip): reduce the batch's 32 block-minima, recompute keys,
// scatter surviving points' features with atomics.
__global__ __launch_bounds__(TPB) void kB(const float* __restrict__ x,
                                          const int* __restrict__ bm,
                                          float* __restrict__ out) {
    const int bid = blockIdx.x, t = threadIdx.x;
    const int b = bid >> 5;
    const int n = ((bid & 31) << 8) | t;

    __shared__ int offsh[2];
    int m0 = 0x7fffffff, m1 = 0x7fffffff;
    if (t < BPB) { m0 = bm[(b * BPB + t) * 2]; m1 = bm[(b * BPB + t) * 2 + 1]; }
    if (t < 64) {
        for (int o = 32; o; o >>= 1) {
            m0 = min(m0, __shfl_down(m0, o));
            m1 = min(m1, __shfl_down(m1, o));
        }
        if (t == 0) { offsh[0] = m0; offsh[1] = m1; }
    }

    int g0, g1, r0, r1;
    compute_point(x, b, n, g0, g1, r0, r1);
    __syncthreads();
    const int c0 = g0 - offsh[0], c1 = g1 - offsh[1];  // >= 0 always
    if (c0 < SSZ && c1 < SSZ) {
        int i = c0 / 3, j = c1 / 3;  // c mod 3 == pts_pick -> exact sub-grid hit
        const float* xb = x + (size_t)b * 6 * NPT + n;
        float* o = out + (size_t)b * 3 * GSZ * GSZ + (size_t)i * GSZ + j;
        atomicAdd(o + 0 * GSZ * GSZ, xb[3 * NPT]);
        atomicAdd(o + 1 * GSZ * GSZ, xb[4 * NPT]);
        atomicAdd(o + 2 * GSZ * GSZ, xb[5 * NPT]);
    }
}

// ---- fallback (round-2 fused single kernel) if ws is too small ----
#define FTPB 1024
#define FPPT (NPT / FTPB)
#define FZPT (3 * GSZ * GSZ / 4 / FTPB)
__global__ __launch_bounds__(FTPB) void kfused(const float* __restrict__ x,
                                               float* __restrict__ out) {
    const int b = blockIdx.x;
    const int t = threadIdx.x;
    __shared__ int pk[NPT];
    __shared__ int red0[16], red1[16], offsh[2];
    float4* ob4 = (float4*)(out + (size_t)b * 3 * GSZ * GSZ);
    const float4 z4 = make_float4(0.f, 0.f, 0.f, 0.f);
#pragma unroll
    for (int k = 0; k < FZPT; ++k) ob4[t + k * FTPB] = z4;
    int m0 = 0x7fffffff, m1 = 0x7fffffff;
#pragma unroll
    for (int k = 0; k < FPPT; ++k) {
        int n = t + k * FTPB;
        int g0, g1, r0, r1;
        compute_point(x, b, n, g0, g1, r0, r1);
        m0 = min(m0, g0 - r0);
        m1 = min(m1, g1 - r1);
        pk[n] = (g0 & 0xffff) | (g1 << 16);
    }
    for (int o = 32; o; o >>= 1) {
        m0 = min(m0, __shfl_down(m0, o));
        m1 = min(m1, __shfl_down(m1, o));
    }
    const int w = t >> 6;
    if ((t & 63) == 0) { red0[w] = m0; red1[w] = m1; }
    __syncthreads();
    if (t == 0) {
        int a0 = red0[0], a1 = red1[0];
        for (int i = 1; i < FTPB / 64; ++i) { a0 = min(a0, red0[i]); a1 = min(a1, red1[i]); }
        offsh[0] = a0; offsh[1] = a1;
    }
    __syncthreads();
    const int off0 = offsh[0], off1 = offsh[1];
    const float* xb = x + (size_t)b * 6 * NPT;
    float* ob = out + (size_t)b * 3 * GSZ * GSZ;
#pragma unroll
    for (int k = 0; k < FPPT; ++k) {
        int n = t + k * FTPB;
        int p = pk[n];
        int g0 = (int)(short)(p & 0xffff);
        int g1 = p >> 16;
        int c0 = g0 - off0, c1 = g1 - off1;
        if (c0 < SSZ && c1 < SSZ) {
            int i = c0 / 3, j = c1 / 3;
            float* o = ob + (size_t)i * GSZ + j;
            atomicAdd(o + 0 * GSZ * GSZ, xb[3 * NPT + n]);
            atomicAdd(o + 1 * GSZ * GSZ, xb[4 * NPT + n]);
            atomicAdd(o + 2 * GSZ * GSZ, xb[5 * NPT + n]);
        }
    }
}

extern "C" void kernel_launch(void* const* d_in, const int* in_sizes, int n_in,
                              void* d_out, int out_size, void* d_ws, size_t ws_size,
                              hipStream_t stream) {
    const float* x = (const float*)d_in[0];
    float* out = (float*)d_out;
    if (ws_size >= (size_t)NBLK * 2 * sizeof(int)) {
        int* bm = (int*)d_ws;   // 2048 min-pairs
        kA<<<NBLK, TPB, 0, stream>>>(x, out, bm);
        kB<<<NBLK, TPB, 0, stream>>>(x, bm, out);
    } else {
        kfused<<<NB, FTPB, 0, stream>>>(x, out);
    }
}